// Round 6
// baseline (5861.135 us; speedup 1.0000x reference)
//
#include <hip/hip_runtime.h>

#define C_CLUST 8
#define N_PAT   16384
#define D_FEAT  1024
#define DQ_DIM  128
#define K_TOP   128

// PROBE multipliers — divide top-5 dur_us by these to get per-rep cost
#define REP_PREP   80
#define REP_SCORE  6
#define REP_TOPK   25
#define REP_GATHER 80
#define REP_FUSION 50

// 1/sqrt(128) and 1/sqrt(1024)
#define INV_S128 0.08838834764831844055
#define INV_S1024 0.03125

// ---------- helpers ----------
__device__ inline unsigned f2key(float f) {
    unsigned u = __float_as_uint(f);
    return (u & 0x80000000u) ? ~u : (u | 0x80000000u);
}
__device__ inline float key2f(unsigned k) {
    unsigned u = (k & 0x80000000u) ? (k ^ 0x80000000u) : ~k;
    return __uint_as_float(u);
}

// ---------- kernel 1: per-cluster qk (f64), b0, r = Wq @ qk ----------
__global__ __launch_bounds__(1024) void prep_kernel(
    const float* __restrict__ key_feats,  // [C,1,D]
    const float* __restrict__ Wq,         // [D,DQ]
    const float* __restrict__ bq,         // [DQ]
    double* __restrict__ r,               // [C][D]
    double* __restrict__ b0)              // [C]
{
    __shared__ float keyrow[D_FEAT];
    __shared__ double part[8][DQ_DIM];
    __shared__ double qk_lds[DQ_DIM];
    __shared__ double prod[DQ_DIM];
    const int c = blockIdx.x;
    const int tid = threadIdx.x;           // 1024 threads
    const int lane = tid & 63, wv = tid >> 6;

#pragma unroll 1
    for (int rep = 0; rep < REP_PREP; ++rep) {
        asm volatile("" ::: "memory");
        keyrow[tid] = key_feats[c * D_FEAT + tid];
        __syncthreads();

        {   // 8-way split-d partial dot: qk[j] = key . Wq[:,j]
            const int j = tid & 127, s = tid >> 7;
            double acc = 0.0;
            for (int d = s; d < D_FEAT; d += 8)
                acc += (double)keyrow[d] * (double)Wq[d * DQ_DIM + j];
            part[s][j] = acc;
        }
        __syncthreads();

        if (tid < DQ_DIM) {
            double v = part[0][tid];
#pragma unroll
            for (int s2 = 1; s2 < 8; ++s2) v += part[s2][tid];
            v += (double)bq[tid];
            qk_lds[tid] = v;
            prod[tid] = (double)bq[tid] * v;
        }
        __syncthreads();

        if (tid < 64) {            // b0 = bq . qk
            double s = prod[tid] + prod[tid + 64];
#pragma unroll
            for (int o = 32; o > 0; o >>= 1) s += __shfl_xor(s, o, 64);
            if (tid == 0) b0[c] = s;
        }

        // r[d] = Wq[d,:] . qk : 16 waves x 64 outputs each
        {
            const double q0 = qk_lds[lane];
            const double q1 = qk_lds[64 + lane];
            const int d0 = wv * 64;
            for (int d = d0; d < d0 + 64; ++d) {
                double a = (double)Wq[d * DQ_DIM + lane] * q0
                         + (double)Wq[d * DQ_DIM + 64 + lane] * q1;
#pragma unroll
                for (int o = 32; o > 0; o >>= 1) a += __shfl_xor(a, o, 64);
                if (lane == 0) r[c * D_FEAT + d] = a;
            }
        }
        __syncthreads();
    }
}

// ---------- kernel 2: scores — r in VGPRs, 16 rows per wave ----------
__global__ __launch_bounds__(256) void score_kernel(
    const float* __restrict__ feats,      // [C,N,D]
    const double* __restrict__ r,         // [C][D]
    const double* __restrict__ b0,        // [C]
    float* __restrict__ scores)           // [C][N]
{
    const int w    = blockIdx.x * 4 + (threadIdx.x >> 6); // wave id, 0..8191
    const int lane = threadIdx.x & 63;
    const int c  = w >> 10;                // 1024 waves per cluster
    const int n0 = (w & 1023) * 16;        // first row (within cluster)

    const double* rp = r + c * D_FEAT;
    double rr[16];
#pragma unroll
    for (int it = 0; it < 4; ++it)
#pragma unroll
        for (int j = 0; j < 4; ++j)
            rr[it * 4 + j] = rp[it * 256 + lane * 4 + j];
    const double bb = b0[c];

    const float4* fbase = (const float4*)(feats + (size_t)(c * N_PAT + n0) * D_FEAT);
    float* sout = scores + c * N_PAT + n0;

#pragma unroll 1
    for (int rep = 0; rep < REP_SCORE; ++rep) {
        asm volatile("" ::: "memory");
        for (int rI = 0; rI < 16; rI += 2) {
            const float4* fp0 = fbase + (size_t)(rI + 0) * 256;
            const float4* fp1 = fbase + (size_t)(rI + 1) * 256;
            double acc0 = 0.0, acc1 = 0.0;
#pragma unroll
            for (int it = 0; it < 4; ++it) {
                float4 f0 = fp0[it * 64 + lane];
                float4 f1 = fp1[it * 64 + lane];
                acc0 += (double)f0.x * rr[it * 4 + 0];
                acc0 += (double)f0.y * rr[it * 4 + 1];
                acc0 += (double)f0.z * rr[it * 4 + 2];
                acc0 += (double)f0.w * rr[it * 4 + 3];
                acc1 += (double)f1.x * rr[it * 4 + 0];
                acc1 += (double)f1.y * rr[it * 4 + 1];
                acc1 += (double)f1.z * rr[it * 4 + 2];
                acc1 += (double)f1.w * rr[it * 4 + 3];
            }
#pragma unroll
            for (int o = 32; o > 0; o >>= 1) {
                acc0 += __shfl_xor(acc0, o, 64);
                acc1 += __shfl_xor(acc1, o, 64);
            }
            if (lane == 0) {
                sout[rI + 0] = (float)(acc0 + bb);
                sout[rI + 1] = (float)(acc1 + bb);
            }
        }
    }
}

// ---------- kernel 3: softmax stats + BALLOT radix-select top-128 (sorted) + A_ ----------
__global__ __launch_bounds__(1024) void topk_kernel(
    const float* __restrict__ scores,     // [C][N]
    int* __restrict__ top_idx,            // [C][K]
    double* __restrict__ Aw)              // [C][K]
{
    const int c = blockIdx.x;
    const int tid = threadIdx.x;
    const int lane = tid & 63, wid = tid >> 6;

    __shared__ double   red_d[16];
    __shared__ unsigned red_u[16];
    __shared__ unsigned bcast_u;
    __shared__ double   bcast_d;
    __shared__ unsigned hist16[16][16];    // [wave][bucket]
    __shared__ unsigned total16[16];
    __shared__ unsigned bcast_b, bcast_need;
    __shared__ int cntG, cntE;
    __shared__ int idxG[K_TOP];
    __shared__ int idxE[256];
    __shared__ int list[K_TOP];
    __shared__ unsigned long long pairs[K_TOP];
    __shared__ double pd[K_TOP];
    __shared__ double red2[2];

#pragma unroll 1
    for (int rep = 0; rep < REP_TOPK; ++rep) {
        asm volatile("" ::: "memory");
        // 16 scores per thread, register-resident
        float sv[16];
        unsigned uk[16];
#pragma unroll
        for (int k = 0; k < 16; ++k) {
            sv[k] = scores[c * N_PAT + k * 1024 + tid];
            uk[k] = f2key(sv[k]);
        }

        // block max
        unsigned mk = 0;
#pragma unroll
        for (int k = 0; k < 16; ++k) mk = max(mk, uk[k]);
#pragma unroll
        for (int o = 32; o > 0; o >>= 1) mk = max(mk, __shfl_xor(mk, o, 64));
        if (lane == 0) red_u[wid] = mk;
        __syncthreads();
        if (tid == 0) {
            unsigned m = 0;
            for (int i = 0; i < 16; ++i) m = max(m, red_u[i]);
            bcast_u = m;
        }
        __syncthreads();
        const double m_t = (double)key2f(bcast_u) * INV_S128;

        // Z = sum exp(s/sqrt(128) - m_t)
        double zs = 0.0;
#pragma unroll
        for (int k = 0; k < 16; ++k)
            zs += (double)__expf((float)((double)sv[k] * INV_S128 - m_t));
#pragma unroll
        for (int o = 32; o > 0; o >>= 1) zs += __shfl_xor(zs, o, 64);
        if (lane == 0) red_d[wid] = zs;
        __syncthreads();
        if (tid == 0) {
            double z = 0.0;
            for (int i = 0; i < 16; ++i) z += red_d[i];
            bcast_d = z;
        }
        __syncthreads();
        const double Z = bcast_d;

        // ---- ballot radix select (4-bit nibbles, 8 passes, no atomics) ----
        unsigned pref = 0;
        int need = K_TOP;
        for (int p = 7; p >= 0; --p) {
            const unsigned hmask = (p == 7) ? 0u : (0xFFFFFFFFu << (4 * (p + 1)));
            const unsigned b = (unsigned)lane & 15u;
            unsigned cnt = 0;
#pragma unroll
            for (int k = 0; k < 16; ++k) {
                bool act = (uk[k] & hmask) == pref;
                unsigned nib = (uk[k] >> (4 * p)) & 15u;
                unsigned long long mact = __ballot(act);
                unsigned long long m0 = __ballot((nib & 1u) != 0u);
                unsigned long long m1 = __ballot((nib & 2u) != 0u);
                unsigned long long m2 = __ballot((nib & 4u) != 0u);
                unsigned long long m3 = __ballot((nib & 8u) != 0u);
                unsigned long long sel = ((b & 1u) ? m0 : ~m0)
                                       & ((b & 2u) ? m1 : ~m1)
                                       & ((b & 4u) ? m2 : ~m2)
                                       & ((b & 8u) ? m3 : ~m3) & mact;
                cnt += (unsigned)__popcll(sel);
            }
            if (lane < 16) hist16[wid][lane] = cnt;
            __syncthreads();
            if (tid < 16) {
                unsigned t = 0;
#pragma unroll
                for (int wv2 = 0; wv2 < 16; ++wv2) t += hist16[wv2][tid];
                total16[tid] = t;
            }
            __syncthreads();
            if (tid < 16) {
                unsigned s = 0;
                for (int b2 = tid; b2 < 16; ++b2) s += total16[b2];
                unsigned hi = s - total16[tid];
                if (s >= (unsigned)need && hi < (unsigned)need) {
                    bcast_b = (unsigned)tid;
                    bcast_need = (unsigned)need - hi;
                }
            }
            __syncthreads();
            pref |= bcast_b << (4 * p);
            need = (int)bcast_need;
            __syncthreads();
        }
        const unsigned lo = pref;

        // collect
        if (tid == 0) { cntG = 0; cntE = 0; }
        __syncthreads();
#pragma unroll
        for (int k = 0; k < 16; ++k) {
            int n = k * 1024 + tid;
            if (uk[k] > lo) {
                int p = atomicAdd(&cntG, 1);
                idxG[p] = n;
            } else if (uk[k] == lo) {
                int p = atomicAdd(&cntE, 1);
                if (p < 256) idxE[p] = n;
            }
        }
        __syncthreads();
        const int nG = cntG;
        const int nE = min(cntE, 256);
        if (tid == 0) {
            for (int i = 1; i < nE; ++i) {
                int v = idxE[i]; int j = i - 1;
                while (j >= 0 && idxE[j] > v) { idxE[j + 1] = idxE[j]; --j; }
                idxE[j + 1] = v;
            }
        }
        __syncthreads();
        if (tid < K_TOP) list[tid] = (tid < nG) ? idxG[tid] : idxE[tid - nG];
        __syncthreads();

        // composite sort key: value desc, index asc  -> sort u64 descending
        if (tid < K_TOP) {
            int idx = list[tid];
            unsigned key = f2key(scores[c * N_PAT + idx]);
            pairs[tid] = ((unsigned long long)key << 32) | (unsigned)(~(unsigned)idx);
        }
        for (int size = 2; size <= K_TOP; size <<= 1) {
            for (int stride = size >> 1; stride > 0; stride >>= 1) {
                __syncthreads();
                if (tid < K_TOP) {
                    int p = tid ^ stride;
                    if (p > tid) {
                        unsigned long long a = pairs[tid], b2 = pairs[p];
                        bool desc = ((tid & size) == 0);
                        if (desc ? (a < b2) : (a > b2)) { pairs[tid] = b2; pairs[p] = a; }
                    }
                }
            }
        }
        __syncthreads();

        // top_vals p_i and A_ = softmax(p/32)
        if (tid < K_TOP) {
            unsigned long long pr = pairs[tid];
            unsigned key = (unsigned)(pr >> 32);
            int idx = (int)(~(unsigned)(pr & 0xFFFFFFFFull));
            top_idx[c * K_TOP + tid] = idx;
            double s = (double)key2f(key);
            pd[tid] = exp(s * INV_S128 - m_t) / Z;
        }
        __syncthreads();
        if (tid < K_TOP) {
            double e = exp((pd[tid] - pd[0]) * INV_S1024);
            double se = e;
#pragma unroll
            for (int o = 32; o > 0; o >>= 1) se += __shfl_xor(se, o, 64);
            if (lane == 0) red2[wid] = se;
        }
        __syncthreads();
        if (tid < K_TOP) {
            double tot = red2[0] + red2[1];
            double e = exp((pd[tid] - pd[0]) * INV_S1024);
            Aw[c * K_TOP + tid] = e / tot;
        }
        __syncthreads();
    }
}

// ---------- kernel 4: fused gather (rows -> out) + partial weighted sum ----------
__global__ __launch_bounds__(256) void gather_wsum_kernel(
    const float* __restrict__ feats,
    const int* __restrict__ top_idx,
    const double* __restrict__ Aw,
    float* __restrict__ out,              // [C*K, D] at offset 0
    double* __restrict__ w_part)          // [C][4][D]
{
    __shared__ double sa[32];
    __shared__ int sidx[32];
    const int b = blockIdx.x;
    const int c = b >> 4, quarter = (b >> 2) & 3, ich = b & 3;
    const int tid = threadIdx.x;           // 256

#pragma unroll 1
    for (int rep = 0; rep < REP_GATHER; ++rep) {
        asm volatile("" ::: "memory");
        if (tid < 32) {
            sa[tid] = Aw[c * K_TOP + ich * 32 + tid];
            sidx[tid] = top_idx[c * K_TOP + ich * 32 + tid];
        }
        __syncthreads();
        const int d = quarter * 256 + tid;
        const float* fc = feats + (size_t)c * N_PAT * D_FEAT + d;
        float* oc = out + ((size_t)c * K_TOP + ich * 32) * D_FEAT + d;
        double a0 = 0.0, a1 = 0.0, a2 = 0.0, a3 = 0.0;
#pragma unroll 2
        for (int i = 0; i < 32; i += 4) {
            float v0 = fc[(size_t)sidx[i + 0] * D_FEAT];
            float v1 = fc[(size_t)sidx[i + 1] * D_FEAT];
            float v2 = fc[(size_t)sidx[i + 2] * D_FEAT];
            float v3 = fc[(size_t)sidx[i + 3] * D_FEAT];
            oc[(size_t)(i + 0) * D_FEAT] = v0;
            oc[(size_t)(i + 1) * D_FEAT] = v1;
            oc[(size_t)(i + 2) * D_FEAT] = v2;
            oc[(size_t)(i + 3) * D_FEAT] = v3;
            a0 += sa[i + 0] * (double)v0;
            a1 += sa[i + 1] * (double)v1;
            a2 += sa[i + 2] * (double)v2;
            a3 += sa[i + 3] * (double)v3;
        }
        w_part[((size_t)(c * 4 + ich)) * D_FEAT + d] = (a0 + a1) + (a2 + a3);
        __syncthreads();
    }
}

// ---------- kernel 5a: fusion partials — split-K (8 chunks of 128) ----------
__global__ __launch_bounds__(256) void fusion_part_kernel(
    const double* __restrict__ w_part,    // [C][4][D]
    const float* __restrict__ Wv,         // [D,D]
    double* __restrict__ part_f)          // [8][8192]
{
    __shared__ double w_chunk[128];
    const int b = blockIdx.x;
    const int q = b >> 5, g = b & 31;
    const int tid = threadIdx.x;           // 256
    const int c = g >> 2;
    const int t0 = g * 256 + tid;          // output index 0..8191
    const int dp = (g & 3) * 256 + tid;

#pragma unroll 1
    for (int rep = 0; rep < REP_FUSION; ++rep) {
        asm volatile("" ::: "memory");
        if (tid < 128) {
            double s = 0.0;
#pragma unroll
            for (int ich = 0; ich < 4; ++ich)
                s += w_part[((size_t)(c * 4 + ich)) * D_FEAT + q * 128 + tid];
            w_chunk[tid] = s;
        }
        __syncthreads();

        const float* wvp = Wv + (size_t)(q * 128) * D_FEAT + dp;
        double a0 = 0.0, a1 = 0.0, a2 = 0.0, a3 = 0.0;
#pragma unroll 4
        for (int d = 0; d < 128; d += 4) {
            a0 += w_chunk[d + 0] * (double)wvp[(size_t)(d + 0) * D_FEAT];
            a1 += w_chunk[d + 1] * (double)wvp[(size_t)(d + 1) * D_FEAT];
            a2 += w_chunk[d + 2] * (double)wvp[(size_t)(d + 2) * D_FEAT];
            a3 += w_chunk[d + 3] * (double)wvp[(size_t)(d + 3) * D_FEAT];
        }
        part_f[(size_t)q * 8192 + t0] = (a0 + a1) + (a2 + a3);
        __syncthreads();
    }
}

// ---------- kernel 5b: combine fusion partials + bias ----------
__global__ __launch_bounds__(256) void fusion_comb_kernel(
    const double* __restrict__ part_f,    // [8][8192]
    const float* __restrict__ bv,         // [D]
    float* __restrict__ out)              // fusion at offset C*K*D
{
    const int t = blockIdx.x * 256 + threadIdx.x;   // 0..8191
    const int dp = t & 1023;
    double acc = (double)bv[dp];
#pragma unroll
    for (int q = 0; q < 8; ++q) acc += part_f[(size_t)q * 8192 + t];
    out[(size_t)(C_CLUST * K_TOP * D_FEAT) + t] = (float)acc;
}

extern "C" void kernel_launch(void* const* d_in, const int* in_sizes, int n_in,
                              void* d_out, int out_size, void* d_ws, size_t ws_size,
                              hipStream_t stream) {
    const float* feats     = (const float*)d_in[0];  // [8,16384,1024]
    const float* key_feats = (const float*)d_in[1];  // [8,1,1024]
    const float* Wq        = (const float*)d_in[2];  // [1024,128]
    const float* bq        = (const float*)d_in[3];  // [128]
    const float* Wv        = (const float*)d_in[4];  // [1024,1024]
    const float* bv        = (const float*)d_in[5];  // [1024]
    float* out = (float*)d_out;

    char* ws = (char*)d_ws;
    float*  scores  = (float*)(ws + 0);         // 8*16384*4      = 524288
    double* r       = (double*)(ws + 524288);   // 8*1024*8       = 65536
    double* b0      = (double*)(ws + 589824);   // 8*8            = 64
    int*    top_idx = (int*)(ws + 589888);      // 8*128*4        = 4096
    double* Aw      = (double*)(ws + 593984);   // 8*128*8        = 8192
    double* w_part  = (double*)(ws + 602176);   // 8*4*1024*8     = 262144
    double* part_f  = (double*)(ws + 864320);   // 8*8192*8       = 524288  (end 1388608)

    hipLaunchKernelGGL(prep_kernel,        dim3(C_CLUST), dim3(1024), 0, stream, key_feats, Wq, bq, r, b0);
    hipLaunchKernelGGL(score_kernel,       dim3(2048),    dim3(256),  0, stream, feats, r, b0, scores);
    hipLaunchKernelGGL(topk_kernel,        dim3(C_CLUST), dim3(1024), 0, stream, scores, top_idx, Aw);
    hipLaunchKernelGGL(gather_wsum_kernel, dim3(128),     dim3(256),  0, stream, feats, top_idx, Aw, out, w_part);
    hipLaunchKernelGGL(fusion_part_kernel, dim3(256),     dim3(256),  0, stream, w_part, Wv, part_f);
    hipLaunchKernelGGL(fusion_comb_kernel, dim3(32),      dim3(256),  0, stream, part_f, bv, out);
}

// Round 7
// 213.124 us; speedup vs baseline: 27.5011x; 27.5011x over previous
//
#include <hip/hip_runtime.h>

#define C_CLUST 8
#define N_PAT   16384
#define D_FEAT  1024
#define DQ_DIM  128
#define K_TOP   128

// 1/sqrt(128) and 1/sqrt(1024)
#define INV_S128 0.08838834764831844055
#define INV_S1024 0.03125

// ---------- helpers ----------
__device__ inline unsigned f2key(float f) {
    unsigned u = __float_as_uint(f);
    return (u & 0x80000000u) ? ~u : (u | 0x80000000u);
}
__device__ inline float key2f(unsigned k) {
    unsigned u = (k & 0x80000000u) ? (k ^ 0x80000000u) : ~k;
    return __uint_as_float(u);
}

// ---------- kernel 1a: qk partials — block (c, sg) covers 64 d's, thread = j ----------
__global__ __launch_bounds__(128) void qk_kernel(
    const float* __restrict__ key_feats,  // [C,1,D]
    const float* __restrict__ Wq,         // [D,DQ]
    double* __restrict__ qk_part)         // [C][16][DQ]
{
    const int b = blockIdx.x;              // c*16 + sg
    const int c = b >> 4, sg = b & 15;
    const int j = threadIdx.x;             // 0..127
    const int d0 = sg * 64;
    double acc = 0.0;
#pragma unroll 4
    for (int d = d0; d < d0 + 64; ++d)
        acc += (double)key_feats[c * D_FEAT + d] * (double)Wq[d * DQ_DIM + j];
    qk_part[(size_t)(c * 16 + sg) * DQ_DIM + j] = acc;
}

// ---------- kernel 1b: r[c][d] = Wq[d,:] . (qk_sum + bq); d==0 wave also emits b0 ----------
__global__ __launch_bounds__(256) void r_kernel(
    const float* __restrict__ Wq,         // [D,DQ]
    const float* __restrict__ bq,         // [DQ]
    const double* __restrict__ qk_part,   // [C][16][DQ]
    double* __restrict__ r,               // [C][D]
    double* __restrict__ b0)              // [C]
{
    const int w = blockIdx.x * 4 + (threadIdx.x >> 6);   // 0..8191
    const int lane = threadIdx.x & 63;
    const int c = w >> 10, d = w & (D_FEAT - 1);

    double q0 = (double)bq[lane];
    double q1 = (double)bq[64 + lane];
#pragma unroll
    for (int sg = 0; sg < 16; ++sg) {
        q0 += qk_part[(size_t)(c * 16 + sg) * DQ_DIM + lane];
        q1 += qk_part[(size_t)(c * 16 + sg) * DQ_DIM + 64 + lane];
    }

    double a = (double)Wq[d * DQ_DIM + lane] * q0
             + (double)Wq[d * DQ_DIM + 64 + lane] * q1;
#pragma unroll
    for (int o = 32; o > 0; o >>= 1) a += __shfl_xor(a, o, 64);
    if (lane == 0) r[c * D_FEAT + d] = a;

    if (d == 0) {   // this wave also computes b0[c] = bq . qk
        double p = (double)bq[lane] * q0 + (double)bq[64 + lane] * q1;
#pragma unroll
        for (int o = 32; o > 0; o >>= 1) p += __shfl_xor(p, o, 64);
        if (lane == 0) b0[c] = p;
    }
}

// ---------- kernel 2: scores — r in VGPRs, 16 rows per wave ----------
__global__ __launch_bounds__(256) void score_kernel(
    const float* __restrict__ feats,      // [C,N,D]
    const double* __restrict__ r,         // [C][D]
    const double* __restrict__ b0,        // [C]
    float* __restrict__ scores)           // [C][N]
{
    const int w    = blockIdx.x * 4 + (threadIdx.x >> 6); // wave id, 0..8191
    const int lane = threadIdx.x & 63;
    const int c  = w >> 10;                // 1024 waves per cluster
    const int n0 = (w & 1023) * 16;        // first row (within cluster)

    const double* rp = r + c * D_FEAT;
    double rr[16];
#pragma unroll
    for (int it = 0; it < 4; ++it)
#pragma unroll
        for (int j = 0; j < 4; ++j)
            rr[it * 4 + j] = rp[it * 256 + lane * 4 + j];
    const double bb = b0[c];

    const float4* fbase = (const float4*)(feats + (size_t)(c * N_PAT + n0) * D_FEAT);
    float* sout = scores + c * N_PAT + n0;

    for (int rI = 0; rI < 16; rI += 2) {   // 2 rows in flight to overlap reduce latency
        const float4* fp0 = fbase + (size_t)(rI + 0) * 256;
        const float4* fp1 = fbase + (size_t)(rI + 1) * 256;
        double acc0 = 0.0, acc1 = 0.0;
#pragma unroll
        for (int it = 0; it < 4; ++it) {
            float4 f0 = fp0[it * 64 + lane];
            float4 f1 = fp1[it * 64 + lane];
            acc0 += (double)f0.x * rr[it * 4 + 0];
            acc0 += (double)f0.y * rr[it * 4 + 1];
            acc0 += (double)f0.z * rr[it * 4 + 2];
            acc0 += (double)f0.w * rr[it * 4 + 3];
            acc1 += (double)f1.x * rr[it * 4 + 0];
            acc1 += (double)f1.y * rr[it * 4 + 1];
            acc1 += (double)f1.z * rr[it * 4 + 2];
            acc1 += (double)f1.w * rr[it * 4 + 3];
        }
#pragma unroll
        for (int o = 32; o > 0; o >>= 1) {
            acc0 += __shfl_xor(acc0, o, 64);
            acc1 += __shfl_xor(acc1, o, 64);
        }
        if (lane == 0) {
            sout[rI + 0] = (float)(acc0 + bb);
            sout[rI + 1] = (float)(acc1 + bb);
        }
    }
}

// ---------- kernel 3: softmax stats + BALLOT radix-select top-128 (sorted) + A_ ----------
__global__ __launch_bounds__(1024) void topk_kernel(
    const float* __restrict__ scores,     // [C][N]
    int* __restrict__ top_idx,            // [C][K]
    double* __restrict__ Aw)              // [C][K]
{
    const int c = blockIdx.x;
    const int tid = threadIdx.x;
    const int lane = tid & 63, wid = tid >> 6;

    __shared__ double   red_d[16];
    __shared__ unsigned red_u[16];
    __shared__ unsigned bcast_u;
    __shared__ double   bcast_d;
    __shared__ unsigned hist16[16][16];    // [wave][bucket]
    __shared__ unsigned total16[16];
    __shared__ unsigned bcast_b, bcast_need;
    __shared__ int cntG, cntE;
    __shared__ int idxG[K_TOP];
    __shared__ int idxE[256];
    __shared__ int list[K_TOP];
    __shared__ unsigned long long pairs[K_TOP];
    __shared__ double pd[K_TOP];
    __shared__ double red2[2];

    // 16 scores per thread, register-resident
    float sv[16];
    unsigned uk[16];
#pragma unroll
    for (int k = 0; k < 16; ++k) {
        sv[k] = scores[c * N_PAT + k * 1024 + tid];
        uk[k] = f2key(sv[k]);
    }

    // block max
    unsigned mk = 0;
#pragma unroll
    for (int k = 0; k < 16; ++k) mk = max(mk, uk[k]);
#pragma unroll
    for (int o = 32; o > 0; o >>= 1) mk = max(mk, __shfl_xor(mk, o, 64));
    if (lane == 0) red_u[wid] = mk;
    __syncthreads();
    if (tid == 0) {
        unsigned m = 0;
        for (int i = 0; i < 16; ++i) m = max(m, red_u[i]);
        bcast_u = m;
    }
    __syncthreads();
    const double m_t = (double)key2f(bcast_u) * INV_S128;

    // Z = sum exp(s/sqrt(128) - m_t)   (f32 exp, f64 sum: only a common scale on pd)
    double zs = 0.0;
#pragma unroll
    for (int k = 0; k < 16; ++k)
        zs += (double)__expf((float)((double)sv[k] * INV_S128 - m_t));
#pragma unroll
    for (int o = 32; o > 0; o >>= 1) zs += __shfl_xor(zs, o, 64);
    if (lane == 0) red_d[wid] = zs;
    __syncthreads();
    if (tid == 0) {
        double z = 0.0;
        for (int i = 0; i < 16; ++i) z += red_d[i];
        bcast_d = z;
    }
    __syncthreads();
    const double Z = bcast_d;

    // ---- ballot radix select (4-bit nibbles, 8 passes, no atomics) ----
    unsigned pref = 0;
    int need = K_TOP;
    for (int p = 7; p >= 0; --p) {
        const unsigned hmask = (p == 7) ? 0u : (0xFFFFFFFFu << (4 * (p + 1)));
        const unsigned b = (unsigned)lane & 15u;
        unsigned cnt = 0;
#pragma unroll
        for (int k = 0; k < 16; ++k) {
            bool act = (uk[k] & hmask) == pref;
            unsigned nib = (uk[k] >> (4 * p)) & 15u;
            unsigned long long mact = __ballot(act);
            unsigned long long m0 = __ballot((nib & 1u) != 0u);
            unsigned long long m1 = __ballot((nib & 2u) != 0u);
            unsigned long long m2 = __ballot((nib & 4u) != 0u);
            unsigned long long m3 = __ballot((nib & 8u) != 0u);
            unsigned long long sel = ((b & 1u) ? m0 : ~m0)
                                   & ((b & 2u) ? m1 : ~m1)
                                   & ((b & 4u) ? m2 : ~m2)
                                   & ((b & 8u) ? m3 : ~m3) & mact;
            cnt += (unsigned)__popcll(sel);
        }
        if (lane < 16) hist16[wid][lane] = cnt;
        __syncthreads();
        if (tid < 16) {
            unsigned t = 0;
#pragma unroll
            for (int wv2 = 0; wv2 < 16; ++wv2) t += hist16[wv2][tid];
            total16[tid] = t;
        }
        __syncthreads();
        if (tid < 16) {
            unsigned s = 0;
            for (int b2 = tid; b2 < 16; ++b2) s += total16[b2];
            unsigned hi = s - total16[tid];
            if (s >= (unsigned)need && hi < (unsigned)need) {
                bcast_b = (unsigned)tid;
                bcast_need = (unsigned)need - hi;
            }
        }
        __syncthreads();
        pref |= bcast_b << (4 * p);
        need = (int)bcast_need;
        __syncthreads();
    }
    const unsigned lo = pref;

    // collect: key > lo definitely in; key == lo fills remainder by smallest index
    if (tid == 0) { cntG = 0; cntE = 0; }
    __syncthreads();
#pragma unroll
    for (int k = 0; k < 16; ++k) {
        int n = k * 1024 + tid;
        if (uk[k] > lo) {
            int p = atomicAdd(&cntG, 1);
            idxG[p] = n;
        } else if (uk[k] == lo) {
            int p = atomicAdd(&cntE, 1);
            if (p < 256) idxE[p] = n;
        }
    }
    __syncthreads();
    const int nG = cntG;
    const int nE = min(cntE, 256);
    if (tid == 0) {
        for (int i = 1; i < nE; ++i) {
            int v = idxE[i]; int j = i - 1;
            while (j >= 0 && idxE[j] > v) { idxE[j + 1] = idxE[j]; --j; }
            idxE[j + 1] = v;
        }
    }
    __syncthreads();
    if (tid < K_TOP) list[tid] = (tid < nG) ? idxG[tid] : idxE[tid - nG];
    __syncthreads();

    // composite sort key: value desc, index asc  -> sort u64 descending
    if (tid < K_TOP) {
        int idx = list[tid];
        unsigned key = f2key(scores[c * N_PAT + idx]);
        pairs[tid] = ((unsigned long long)key << 32) | (unsigned)(~(unsigned)idx);
    }
    for (int size = 2; size <= K_TOP; size <<= 1) {
        for (int stride = size >> 1; stride > 0; stride >>= 1) {
            __syncthreads();
            if (tid < K_TOP) {
                int p = tid ^ stride;
                if (p > tid) {
                    unsigned long long a = pairs[tid], b2 = pairs[p];
                    bool desc = ((tid & size) == 0);
                    if (desc ? (a < b2) : (a > b2)) { pairs[tid] = b2; pairs[p] = a; }
                }
            }
        }
    }
    __syncthreads();

    // top_vals p_i and A_ = softmax(p/32)
    if (tid < K_TOP) {
        unsigned long long pr = pairs[tid];
        unsigned key = (unsigned)(pr >> 32);
        int idx = (int)(~(unsigned)(pr & 0xFFFFFFFFull));
        top_idx[c * K_TOP + tid] = idx;
        double s = (double)key2f(key);
        pd[tid] = exp(s * INV_S128 - m_t) / Z;
    }
    __syncthreads();
    if (tid < K_TOP) {
        double e = exp((pd[tid] - pd[0]) * INV_S1024);   // pd[0] is the max (sorted)
        double se = e;
#pragma unroll
        for (int o = 32; o > 0; o >>= 1) se += __shfl_xor(se, o, 64);
        if (lane == 0) red2[wid] = se;
    }
    __syncthreads();
    if (tid < K_TOP) {
        double tot = red2[0] + red2[1];
        double e = exp((pd[tid] - pd[0]) * INV_S1024);
        Aw[c * K_TOP + tid] = e / tot;
    }
}

// ---------- kernel 4: fused gather (rows -> out) + partial weighted sum ----------
// grid: C * 4(d-quarter) * 4(i-chunk) = 128 blocks
__global__ __launch_bounds__(256) void gather_wsum_kernel(
    const float* __restrict__ feats,
    const int* __restrict__ top_idx,
    const double* __restrict__ Aw,
    float* __restrict__ out,              // [C*K, D] at offset 0
    double* __restrict__ w_part)          // [C][4][D]
{
    __shared__ double sa[32];
    __shared__ int sidx[32];
    const int b = blockIdx.x;
    const int c = b >> 4, quarter = (b >> 2) & 3, ich = b & 3;
    const int tid = threadIdx.x;           // 256
    if (tid < 32) {
        sa[tid] = Aw[c * K_TOP + ich * 32 + tid];
        sidx[tid] = top_idx[c * K_TOP + ich * 32 + tid];
    }
    __syncthreads();
    const int d = quarter * 256 + tid;
    const float* fc = feats + (size_t)c * N_PAT * D_FEAT + d;
    float* oc = out + ((size_t)c * K_TOP + ich * 32) * D_FEAT + d;
    double a0 = 0.0, a1 = 0.0, a2 = 0.0, a3 = 0.0;
#pragma unroll 2
    for (int i = 0; i < 32; i += 4) {
        float v0 = fc[(size_t)sidx[i + 0] * D_FEAT];
        float v1 = fc[(size_t)sidx[i + 1] * D_FEAT];
        float v2 = fc[(size_t)sidx[i + 2] * D_FEAT];
        float v3 = fc[(size_t)sidx[i + 3] * D_FEAT];
        oc[(size_t)(i + 0) * D_FEAT] = v0;
        oc[(size_t)(i + 1) * D_FEAT] = v1;
        oc[(size_t)(i + 2) * D_FEAT] = v2;
        oc[(size_t)(i + 3) * D_FEAT] = v3;
        a0 += sa[i + 0] * (double)v0;
        a1 += sa[i + 1] * (double)v1;
        a2 += sa[i + 2] * (double)v2;
        a3 += sa[i + 3] * (double)v3;
    }
    w_part[((size_t)(c * 4 + ich)) * D_FEAT + d] = (a0 + a1) + (a2 + a3);
}

// ---------- kernel 5: fusion (single kernel, in-block split-K) ----------
// grid: C * 8(dp-chunks of 128) = 64 blocks x 256 thr
__global__ __launch_bounds__(256) void fusion_kernel(
    const double* __restrict__ w_part,    // [C][4][D]
    const float* __restrict__ Wv,         // [D,D]
    const float* __restrict__ bv,         // [D]
    float* __restrict__ out)              // fusion at offset C*K*D
{
    __shared__ double w_lds[D_FEAT];
    __shared__ double partl[2][128];
    const int b = blockIdx.x;
    const int c = b >> 3, dpg = b & 7;
    const int tid = threadIdx.x;           // 256

    for (int d = tid; d < D_FEAT; d += 256) {
        double s = 0.0;
#pragma unroll
        for (int ich = 0; ich < 4; ++ich)
            s += w_part[((size_t)(c * 4 + ich)) * D_FEAT + d];
        w_lds[d] = s;
    }
    __syncthreads();

    const int dpl = tid & 127, half = tid >> 7;
    const int dp = dpg * 128 + dpl;
    const double* wc = w_lds + half * 512;
    const float* wvp = Wv + (size_t)(half * 512) * D_FEAT + dp;
    double a0 = 0.0, a1 = 0.0, a2 = 0.0, a3 = 0.0;
#pragma unroll 2
    for (int d = 0; d < 512; d += 4) {
        a0 += wc[d + 0] * (double)wvp[(size_t)(d + 0) * D_FEAT];
        a1 += wc[d + 1] * (double)wvp[(size_t)(d + 1) * D_FEAT];
        a2 += wc[d + 2] * (double)wvp[(size_t)(d + 2) * D_FEAT];
        a3 += wc[d + 3] * (double)wvp[(size_t)(d + 3) * D_FEAT];
    }
    partl[half][dpl] = (a0 + a1) + (a2 + a3);
    __syncthreads();
    if (half == 0) {
        double acc = (double)bv[dp] + partl[0][dpl] + partl[1][dpl];
        out[(size_t)(C_CLUST * K_TOP * D_FEAT) + c * D_FEAT + dp] = (float)acc;
    }
}

extern "C" void kernel_launch(void* const* d_in, const int* in_sizes, int n_in,
                              void* d_out, int out_size, void* d_ws, size_t ws_size,
                              hipStream_t stream) {
    const float* feats     = (const float*)d_in[0];  // [8,16384,1024]
    const float* key_feats = (const float*)d_in[1];  // [8,1,1024]
    const float* Wq        = (const float*)d_in[2];  // [1024,128]
    const float* bq        = (const float*)d_in[3];  // [128]
    const float* Wv        = (const float*)d_in[4];  // [1024,1024]
    const float* bv        = (const float*)d_in[5];  // [1024]
    float* out = (float*)d_out;

    char* ws = (char*)d_ws;
    float*  scores  = (float*)(ws + 0);         // 8*16384*4      = 524288
    double* qk_part = (double*)(ws + 524288);   // 8*16*128*8     = 131072
    double* r       = (double*)(ws + 655360);   // 8*1024*8       = 65536
    double* b0      = (double*)(ws + 720896);   // 8*8            = 64
    int*    top_idx = (int*)(ws + 720960);      // 8*128*4        = 4096
    double* Aw      = (double*)(ws + 725056);   // 8*128*8        = 8192
    double* w_part  = (double*)(ws + 733248);   // 8*4*1024*8     = 262144  (end 995392)

    hipLaunchKernelGGL(qk_kernel,          dim3(C_CLUST * 16), dim3(128), 0, stream, key_feats, Wq, qk_part);
    hipLaunchKernelGGL(r_kernel,           dim3(2048),    dim3(256),  0, stream, Wq, bq, qk_part, r, b0);
    hipLaunchKernelGGL(score_kernel,       dim3(2048),    dim3(256),  0, stream, feats, r, b0, scores);
    hipLaunchKernelGGL(topk_kernel,        dim3(C_CLUST), dim3(1024), 0, stream, scores, top_idx, Aw);
    hipLaunchKernelGGL(gather_wsum_kernel, dim3(128),     dim3(256),  0, stream, feats, top_idx, Aw, out, w_part);
    hipLaunchKernelGGL(fusion_kernel,      dim3(64),      dim3(256),  0, stream, w_part, Wv, bv, out);
}